// Round 2
// baseline (496.832 us; speedup 1.0000x reference)
//
#include <hip/hip_runtime.h>
#include <math.h>

typedef unsigned short ushort_t;
typedef unsigned int uint_t;
typedef __attribute__((ext_vector_type(8))) short short8;
typedef __attribute__((ext_vector_type(4))) float fx4;

__device__ __forceinline__ float bf16_to_f32(ushort_t u) {
    union { uint_t i; float f; } c;
    c.i = ((uint_t)u) << 16;
    return c.f;
}
__device__ __forceinline__ ushort_t f32_to_bf16(float f) {
    union { float f; uint_t i; } c;
    c.f = f;
    const uint_t x = c.i;
    return (ushort_t)((x + 0x7fffu + ((x >> 16) & 1u)) >> 16);
}

// ---- W transpose + bf16 convert: WT[m][k] = bf16(W[k][m]) ----------------
__global__ void convT_kernel(const float* __restrict__ W,
                             ushort_t* __restrict__ WT, int k, int m) {
    const int idx = blockIdx.x * 256 + threadIdx.x;
    if (idx >= k * m) return;
    const int mm = idx / k;
    const int kk = idx % k;
    WT[idx] = f32_to_bf16(W[(size_t)kk * m + mm]);
}

// ---- MFMA GEMM with B staged in LDS ---------------------------------------
// C[n][TILES*16](bf16) = A[n][K] * B[K][TILES*16], BT[col][K] bf16.
// 4 waves/block, each wave owns 2 row-tiles (32 rows) -> block = 128 rows.
// BT staged in LDS once, XOR-swizzled on 16B chunks (c ^ (row&7)).
// A is register double-buffered: prefetch kc+1 while MFMAing kc.
template <int TILES, bool A_F32, int K>
__global__ __launch_bounds__(256) void gemm_lds_kernel(
    const void* __restrict__ Avoid, const ushort_t* __restrict__ BT,
    ushort_t* __restrict__ C, int n) {
    constexpr int M = TILES * 16;
    constexpr int CH = K / 8;  // 16B chunks per B row
    constexpr int NC = K / 32; // K-chunks
    __shared__ ushort_t lds[M * K];  // 64KB (layer1) / 16KB (layer2)
    const int tid = threadIdx.x;

    // ---- stage BT -> LDS, swizzled ----
#pragma unroll
    for (int i = 0; i < (M * CH + 255) / 256; ++i) {
        const int idx = tid + i * 256;
        if (idx < M * CH) {
            const int row = idx / CH;
            const int c = idx - row * CH;
            *(short8*)&lds[(size_t)(row * CH + (c ^ (row & 7))) * 8] =
                *(const short8*)(BT + (size_t)row * K + c * 8);
        }
    }
    __syncthreads();

    const int wave = tid >> 6;
    const int lane = tid & 63;
    const int l15 = lane & 15;
    const int quad = lane >> 4;
    const int rowbase = blockIdx.x * 128 + wave * 32;
    const int r0 = min(rowbase + l15, n - 1);
    const int r1 = min(rowbase + 16 + l15, n - 1);
    const size_t off0 = (size_t)r0 * K + quad * 8;
    const size_t off1 = (size_t)r1 * K + quad * 8;

    fx4 acc[2][TILES];
#pragma unroll
    for (int rp = 0; rp < 2; ++rp)
#pragma unroll
        for (int t = 0; t < TILES; ++t) acc[rp][t] = (fx4){0.f, 0.f, 0.f, 0.f};

    fx4 c0a, c0b, c1a, c1b, n0a, n0b, n1a, n1b;
    short8 cb0, cb1, nb0, nb1;

    if constexpr (A_F32) {
        const float* A = (const float*)Avoid;
        c0a = *(const fx4*)(A + off0);
        c0b = *(const fx4*)(A + off0 + 4);
        c1a = *(const fx4*)(A + off1);
        c1b = *(const fx4*)(A + off1 + 4);
    } else {
        const ushort_t* A = (const ushort_t*)Avoid;
        cb0 = *(const short8*)(A + off0);
        cb1 = *(const short8*)(A + off1);
    }

#pragma unroll
    for (int kc = 0; kc < NC; ++kc) {
        if (kc + 1 < NC) {
            const int kd = (kc + 1) * 32;
            if constexpr (A_F32) {
                const float* A = (const float*)Avoid;
                n0a = *(const fx4*)(A + off0 + kd);
                n0b = *(const fx4*)(A + off0 + kd + 4);
                n1a = *(const fx4*)(A + off1 + kd);
                n1b = *(const fx4*)(A + off1 + kd + 4);
            } else {
                const ushort_t* A = (const ushort_t*)Avoid;
                nb0 = *(const short8*)(A + off0 + kd);
                nb1 = *(const short8*)(A + off1 + kd);
            }
        }
        short8 bf[TILES];
#pragma unroll
        for (int t = 0; t < TILES; ++t) {
            const int brow = t * 16 + l15;
            const int c = kc * 4 + quad;
            bf[t] = *(const short8*)&lds[(size_t)(brow * CH +
                                                  (c ^ (brow & 7))) * 8];
        }
        short8 af0, af1;
        if constexpr (A_F32) {
            union { short8 v; ushort_t u[8]; } u0, u1;
#pragma unroll
            for (int j = 0; j < 4; ++j) {
                u0.u[j] = f32_to_bf16(c0a[j]);
                u0.u[4 + j] = f32_to_bf16(c0b[j]);
                u1.u[j] = f32_to_bf16(c1a[j]);
                u1.u[4 + j] = f32_to_bf16(c1b[j]);
            }
            af0 = u0.v;
            af1 = u1.v;
        } else {
            af0 = cb0;
            af1 = cb1;
        }
#pragma unroll
        for (int t = 0; t < TILES; ++t) {
            acc[0][t] = __builtin_amdgcn_mfma_f32_16x16x32_bf16(af0, bf[t],
                                                                acc[0][t],
                                                                0, 0, 0);
            acc[1][t] = __builtin_amdgcn_mfma_f32_16x16x32_bf16(af1, bf[t],
                                                                acc[1][t],
                                                                0, 0, 0);
        }
        if (kc + 1 < NC) {
            if constexpr (A_F32) {
                c0a = n0a; c0b = n0b; c1a = n1a; c1b = n1b;
            } else {
                cb0 = nb0; cb1 = nb1;
            }
        }
    }

#pragma unroll
    for (int rp = 0; rp < 2; ++rp) {
        const int crow0 = rowbase + rp * 16 + quad * 4;
#pragma unroll
        for (int t = 0; t < TILES; ++t) {
#pragma unroll
            for (int r = 0; r < 4; ++r) {
                const int rr = crow0 + r;
                if (rr < n)
                    C[(size_t)rr * M + t * 16 + l15] =
                        f32_to_bf16(acc[rp][t][r]);
            }
        }
    }
}

// ------------- per-node attention coefficients a_src, a_dst ---------------
template <int H, int C>
__global__ void att_kernel(const ushort_t* __restrict__ h,
                           const float* __restrict__ att_s,
                           const float* __restrict__ att_d,
                           float* __restrict__ as_, float* __restrict__ ad_,
                           int n) {
    const int idx = blockIdx.x * blockDim.x + threadIdx.x;
    if (idx >= n * H) return;
    const int node = idx / H;
    const int hh = idx % H;
    const ushort_t* hp = h + (size_t)node * H * C + hh * C;
    float s0 = 0.f, s1 = 0.f;
#pragma unroll
    for (int c = 0; c < C; ++c) {
        const float v = bf16_to_f32(hp[c]);
        s0 += v * att_s[hh * C + c];
        s1 += v * att_d[hh * C + c];
    }
    as_[idx] = s0;
    ad_[idx] = s1;
}

// ------------------- CSR build via binned counting sort -------------------
__global__ __launch_bounds__(1024) void hist_kernel(const int* __restrict__ dst,
                                                    int* __restrict__ histG,
                                                    int e, int chunk, int NB,
                                                    int G) {
    __shared__ int hl[512];
    for (int b = threadIdx.x; b < NB; b += 1024) hl[b] = 0;
    __syncthreads();
    const int g = blockIdx.x;
    const int lo = g * chunk;
    const int hi = min(lo + chunk, e);
    for (int i = lo + threadIdx.x; i < hi; i += 1024)
        atomicAdd(&hl[dst[i] >> 8], 1);
    __syncthreads();
    for (int b = threadIdx.x; b < NB; b += 1024) histG[b * G + g] = hl[b];
}

__global__ __launch_bounds__(1024) void scan1_kernel(const int* __restrict__ in,
                                                     int* __restrict__ out,
                                                     int* __restrict__ sums,
                                                     int n) {
    __shared__ int s[1024];
    const int t = threadIdx.x;
    const int i = blockIdx.x * 1024 + t;
    const int v = (i < n) ? in[i] : 0;
    s[t] = v;
    __syncthreads();
    for (int d = 1; d < 1024; d <<= 1) {
        const int x = (t >= d) ? s[t - d] : 0;
        __syncthreads();
        s[t] += x;
        __syncthreads();
    }
    if (i < n) out[i] = s[t] - v;
    if (t == 1023) sums[blockIdx.x] = s[1023];
}

__global__ __launch_bounds__(128) void scan2_kernel(int* sums, int nb) {
    __shared__ int s[128];
    const int t = threadIdx.x;
    const int v = (t < nb) ? sums[t] : 0;
    s[t] = v;
    __syncthreads();
    for (int d = 1; d < 128; d <<= 1) {
        const int x = (t >= d) ? s[t - d] : 0;
        __syncthreads();
        s[t] += x;
        __syncthreads();
    }
    if (t < nb) sums[t] = s[t] - v;
}

__global__ __launch_bounds__(1024) void scan3_kernel(int* __restrict__ out,
                                                     const int* __restrict__ sums,
                                                     int n) {
    const int i = blockIdx.x * 1024 + threadIdx.x;
    if (i < n) out[i] += sums[blockIdx.x];
}

__global__ __launch_bounds__(1024) void bin_kernel(const int* __restrict__ src,
                                                   const int* __restrict__ dst,
                                                   const int* __restrict__ base,
                                                   int2* __restrict__ binned,
                                                   int e, int chunk, int NB,
                                                   int G) {
    __shared__ int cur[512];
    const int g = blockIdx.x;
    for (int b = threadIdx.x; b < NB; b += 1024) cur[b] = base[b * G + g];
    __syncthreads();
    const int lo = g * chunk;
    const int hi = min(lo + chunk, e);
    for (int i = lo + threadIdx.x; i < hi; i += 1024) {
        const int d = dst[i];
        const int p = atomicAdd(&cur[d >> 8], 1);
        binned[p] = make_int2(src[i], d);
    }
}

#define BUILD_CAP 6144
__global__ __launch_bounds__(256) void build_kernel(
    const int2* __restrict__ binned, const int* __restrict__ base,
    int* __restrict__ csr, int* __restrict__ deg, int* __restrict__ offs,
    int e, int n, int NB, int G) {
    __shared__ int2 ep[BUILD_CAP];
    __shared__ int degL[256];
    __shared__ int offL[256];
    __shared__ int curL[256];
    const int b = blockIdx.x;
    const int tid = threadIdx.x;
    const int start = base[b * G];
    const int end = (b == NB - 1) ? e : base[(b + 1) * G];
    const int cnt = end - start;
    const bool stage = (cnt <= BUILD_CAP);
    degL[tid] = 0;
    if (stage)
        for (int i = tid; i < cnt; i += 256) ep[i] = binned[start + i];
    __syncthreads();
    if (stage) {
        for (int i = tid; i < cnt; i += 256) atomicAdd(&degL[ep[i].y & 255], 1);
    } else {
        for (int i = tid; i < cnt; i += 256)
            atomicAdd(&degL[binned[start + i].y & 255], 1);
    }
    __syncthreads();
    const int v = degL[tid];
    offL[tid] = v;
    __syncthreads();
    for (int d = 1; d < 256; d <<= 1) {
        const int x = (tid >= d) ? offL[tid - d] : 0;
        __syncthreads();
        offL[tid] += x;
        __syncthreads();
    }
    const int excl = offL[tid] - v;
    curL[tid] = excl;
    const int node = (b << 8) + tid;
    if (node < n) {
        deg[node] = v;
        offs[node] = start + excl;
    }
    __syncthreads();
    if (stage) {
        for (int i = tid; i < cnt; i += 256) {
            const int p = atomicAdd(&curL[ep[i].y & 255], 1);
            csr[start + p] = ep[i].x;
        }
    } else {
        for (int i = tid; i < cnt; i += 256) {
            const int2 pr = binned[start + i];
            const int p = atomicAdd(&curL[pr.y & 255], 1);
            csr[start + p] = pr.x;
        }
    }
}

// --------- single-pass gather-aggregate + fused softmax denominator -------
// 4 nodes per 256-thread block (1 wave/node). Node-level values forced
// wave-uniform (readfirstlane) so csr/a_src go through the SMEM pipe;
// the only vector loads are the h-row gathers (SGPR base + lane offset).
// Explicit 2-chunk software pipeline with named A/B buffers (static
// indexing; rule #20). Tail chunk is index-clamped + p-masked.
template <int H>
__device__ __forceinline__ float head_sel(const float* __restrict__ a,
                                          int node, int myh) {
    if constexpr (H == 1) {
        return a[node];  // uniform -> s_load
    } else {
        const fx4 v = *(const fx4*)(a + (size_t)node * H);  // s_load_dwordx4
        const float lo = (myh & 1) ? v[1] : v[0];
        const float hi = (myh & 1) ? v[3] : v[2];
        return (myh & 2) ? hi : lo;
    }
}

template <int H, int C, bool DO_ELU, bool OUT_BF16>
__global__ __launch_bounds__(256) void agg_kernel(
    const ushort_t* __restrict__ h, const float* __restrict__ a_src,
    const float* __restrict__ a_dst, const int* __restrict__ csr,
    const int* __restrict__ offs, const int* __restrict__ deg,
    const float* __restrict__ bias, void* __restrict__ outv, int n) {
    constexpr int HC = H * C;
    constexpr int R = HC / 64;  // 2 (layer1) or 1 (layer2)
    constexpr int U = 8;        // edge chunk size
    const int lane = threadIdx.x & 63;
    const int wv = __builtin_amdgcn_readfirstlane((int)(threadIdx.x >> 6));
    const int dst = blockIdx.x * 4 + wv;
    if (dst >= n) return;
    const int start = offs[dst];  // uniform -> s_load
    const int d = deg[dst];       // uniform -> s_load
    const int myh = lane & (H - 1);
    const int ch0 = lane * R;
    const int hh = ch0 / C;
    const float advm = head_sel<H>(a_dst, dst, myh);
    float acc0 = 0.f, acc1 = 0.f;
    float L = 0.f;

    // ---- self-loop term ----
    {
        float e = head_sel<H>(a_src, dst, myh) + advm;
        e = fmaxf(e, 0.2f * e);
        const float p = __expf(e);
        L += p;
        const float a = (H > 1) ? __shfl(p, hh) : p;
        const ushort_t* hp = h + (size_t)dst * HC + ch0;
        if (R == 2) {
            const uint_t v = *(const uint_t*)hp;
            acc0 += a * bf16_to_f32((ushort_t)(v & 0xffffu));
            acc1 += a * bf16_to_f32((ushort_t)(v >> 16));
        } else {
            acc0 += a * bf16_to_f32(hp[0]);
        }
    }

    const int nc = (d + U - 1) / U;  // masked chunks (incl. partial tail)
    const int dm1 = (d > 0) ? d - 1 : 0;

// stage chunk cc: scalar csr -> scalar a_src -> issue h gather, precompute
// masked p. Buffers pX[U] (float) / hX[U] (uint).
#define STAGE(cc, pX, hX)                                                   \
    {                                                                       \
        int sv_[U];                                                         \
        _Pragma("unroll") for (int u = 0; u < U; ++u)                       \
            sv_[u] = csr[start + min((cc) * U + u, dm1)];                   \
        _Pragma("unroll") for (int u = 0; u < U; ++u) {                     \
            const ushort_t* hp_ = h + (size_t)sv_[u] * HC + ch0;            \
            if (R == 2) hX[u] = *(const uint_t*)hp_;                        \
            else hX[u] = (uint_t)(*hp_);                                    \
        }                                                                   \
        _Pragma("unroll") for (int u = 0; u < U; ++u) {                     \
            float e_ = head_sel<H>(a_src, sv_[u], myh) + advm;              \
            e_ = fmaxf(e_, 0.2f * e_);                                      \
            const float p_ = __expf(e_);                                    \
            pX[u] = ((cc) * U + u < d) ? p_ : 0.f;                          \
        }                                                                   \
    }

#define ACCUM(pX, hX)                                                      \
    _Pragma("unroll") for (int u = 0; u < U; ++u) {                        \
        L += pX[u];                                                        \
        const float a_ = (H > 1) ? __shfl(pX[u], hh) : pX[u];              \
        if (R == 2) {                                                      \
            acc0 += a_ * bf16_to_f32((ushort_t)(hX[u] & 0xffffu));         \
            acc1 += a_ * bf16_to_f32((ushort_t)(hX[u] >> 16));             \
        } else {                                                           \
            acc0 += a_ * bf16_to_f32((ushort_t)hX[u]);                     \
        }                                                                  \
    }

    float pA[U], pB[U];
    uint_t hA[U], hB[U];
    if (nc > 0) {
        STAGE(0, pA, hA);
        if (nc > 1) STAGE(1, pB, hB);
        for (int c = 0; c < nc; c += 2) {
            ACCUM(pA, hA);
            if (c + 2 < nc) STAGE(c + 2, pA, hA);
            if (c + 1 < nc) ACCUM(pB, hB);
            if (c + 3 < nc) STAGE(c + 3, pB, hB);
        }
    }
#undef STAGE
#undef ACCUM

    const float Ld = (H > 1) ? __shfl(L, hh) : L;
    const float linv = 1.f / (Ld + 1e-16f);
    float r0 = acc0 * linv + bias[ch0];
    if (DO_ELU) r0 = (r0 > 0.f) ? r0 : (__expf(r0) - 1.f);
    if (R == 2) {
        float r1 = acc1 * linv + bias[ch0 + 1];
        if (DO_ELU) r1 = (r1 > 0.f) ? r1 : (__expf(r1) - 1.f);
        if (OUT_BF16) {
            const uint_t packed =
                (uint_t)f32_to_bf16(r0) | ((uint_t)f32_to_bf16(r1) << 16);
            *(uint_t*)((ushort_t*)outv + (size_t)dst * HC + ch0) = packed;
        } else {
            *(float2*)((float*)outv + (size_t)dst * HC + ch0) =
                make_float2(r0, r1);
        }
    } else {
        if (OUT_BF16)
            ((ushort_t*)outv)[(size_t)dst * HC + ch0] = f32_to_bf16(r0);
        else
            ((float*)outv)[(size_t)dst * HC + ch0] = r0;
    }
}

// --------------------------------------------------------------------------
extern "C" void kernel_launch(void* const* d_in, const int* in_sizes, int n_in,
                              void* d_out, int out_size, void* d_ws,
                              size_t ws_size, hipStream_t stream) {
    const float* x = (const float*)d_in[0];
    const int* ei = (const int*)d_in[1];
    const float* W1 = (const float*)d_in[2];
    const float* att_s1 = (const float*)d_in[3];
    const float* att_d1 = (const float*)d_in[4];
    const float* b1 = (const float*)d_in[5];
    const float* W2 = (const float*)d_in[6];
    const float* att_s2 = (const float*)d_in[7];
    const float* att_d2 = (const float*)d_in[8];
    const float* b2 = (const float*)d_in[9];

    const int N = in_sizes[0] / 256;  // 100000
    const int E = in_sizes[1] / 2;    // 1600000
    const int* srcp = ei;
    const int* dstp = ei + E;

    const int NB = (N + 255) >> 8;  // 391 buckets of 256 nodes
    const int G = 128;
    const int NBG = NB * G;
    const int chunk = (E + G - 1) / G;
    const int nbs = (NBG + 1023) / 1024;

    // workspace layout
    float* as1 = (float*)d_ws;           // N*4
    float* ad1 = as1 + (size_t)N * 4;    // N*4
    float* as2 = ad1 + (size_t)N * 4;    // N
    float* ad2 = as2 + N;                // N
    int* histG = (int*)(ad2 + N);        // NBG
    int* base = histG + NBG;             // NBG
    int* sums = base + NBG;              // 128
    int* deg = sums + 128;               // N
    int* offs = deg + N;                 // N
    int* csr = offs + N;                 // E
    int2* binned = (int2*)(csr + E);     // E pairs (dead after build)
    ushort_t* h1 = (ushort_t*)binned;    // N*128 bf16 (overlays binned)
    ushort_t* h2 = h1 + (size_t)N * 128; // N*64 bf16
    ushort_t* h1p = h2 + (size_t)N * 64; // N*128 bf16 (agg1 out, gemm2 A)
    ushort_t* W1T = h1p + (size_t)N * 128;  // 128*256
    ushort_t* W2T = W1T + 128 * 256;        // 64*128

    // ---- weight transpose + bf16 convert ----
    convT_kernel<<<(256 * 128 + 255) / 256, 256, 0, stream>>>(W1, W1T, 256, 128);
    convT_kernel<<<(128 * 64 + 255) / 256, 256, 0, stream>>>(W2, W2T, 128, 64);

    // ---- CSR build (binned counting sort, no global atomics) ----
    hist_kernel<<<G, 1024, 0, stream>>>(dstp, histG, E, chunk, NB, G);
    scan1_kernel<<<nbs, 1024, 0, stream>>>(histG, base, sums, NBG);
    scan2_kernel<<<1, 128, 0, stream>>>(sums, nbs);
    scan3_kernel<<<nbs, 1024, 0, stream>>>(base, sums, NBG);
    bin_kernel<<<G, 1024, 0, stream>>>(srcp, dstp, base, binned, E, chunk, NB,
                                       G);
    build_kernel<<<NB, 256, 0, stream>>>(binned, base, csr, deg, offs, E, N,
                                         NB, G);

    const int gblk = (N + 127) / 128;  // 782 (128 rows per block)
    const int ablk = (N + 3) / 4;      // 25000 (4 nodes per block)

    // ---- layer 1 ----
    gemm_lds_kernel<8, true, 256><<<gblk, 256, 0, stream>>>(x, W1T, h1, N);
    att_kernel<4, 32><<<(N * 4 + 255) / 256, 256, 0, stream>>>(h1, att_s1,
                                                               att_d1, as1,
                                                               ad1, N);
    agg_kernel<4, 32, true, true><<<ablk, 256, 0, stream>>>(h1, as1, ad1, csr,
                                                            offs, deg, b1,
                                                            h1p, N);

    // ---- layer 2 ----
    gemm_lds_kernel<4, false, 128><<<gblk, 256, 0, stream>>>(h1p, W2T, h2, N);
    att_kernel<1, 64><<<(N + 255) / 256, 256, 0, stream>>>(h2, att_s2, att_d2,
                                                           as2, ad2, N);
    agg_kernel<1, 64, false, false><<<ablk, 256, 0, stream>>>(h2, as2, ad2,
                                                              csr, offs, deg,
                                                              b2, d_out, N);
}

// Round 3
// 439.077 us; speedup vs baseline: 1.1315x; 1.1315x over previous
//
#include <hip/hip_runtime.h>
#include <math.h>

typedef unsigned short ushort_t;
typedef unsigned int uint_t;
typedef __attribute__((ext_vector_type(8))) short short8;
typedef __attribute__((ext_vector_type(4))) float fx4;

__device__ __forceinline__ float bf16_to_f32(ushort_t u) {
    union { uint_t i; float f; } c;
    c.i = ((uint_t)u) << 16;
    return c.f;
}
__device__ __forceinline__ ushort_t f32_to_bf16(float f) {
    union { float f; uint_t i; } c;
    c.f = f;
    const uint_t x = c.i;
    return (ushort_t)((x + 0x7fffu + ((x >> 16) & 1u)) >> 16);
}

// ---- W transpose + bf16 convert: WT[m][k] = bf16(W[k][m]) ----------------
__global__ void convT_kernel(const float* __restrict__ W,
                             ushort_t* __restrict__ WT, int k, int m) {
    const int idx = blockIdx.x * 256 + threadIdx.x;
    if (idx >= k * m) return;
    const int mm = idx / k;
    const int kk = idx % k;
    WT[idx] = f32_to_bf16(W[(size_t)kk * m + mm]);
}

// ---- MFMA GEMM with B staged in LDS ---------------------------------------
// C[n][TILES*16](bf16) = A[n][K] * B[K][TILES*16], BT[col][K] bf16.
// 4 waves/block, each wave owns 2 row-tiles (32 rows) -> block = 128 rows.
// BT staged in LDS once, XOR-swizzled on 16B chunks (c ^ (row&7)).
// A is register double-buffered: prefetch kc+1 while MFMAing kc.
template <int TILES, bool A_F32, int K>
__global__ __launch_bounds__(256) void gemm_lds_kernel(
    const void* __restrict__ Avoid, const ushort_t* __restrict__ BT,
    ushort_t* __restrict__ C, int n) {
    constexpr int M = TILES * 16;
    constexpr int CH = K / 8;  // 16B chunks per B row
    constexpr int NC = K / 32; // K-chunks
    __shared__ ushort_t lds[M * K];  // 64KB (layer1) / 16KB (layer2)
    const int tid = threadIdx.x;

    // ---- stage BT -> LDS, swizzled ----
#pragma unroll
    for (int i = 0; i < (M * CH + 255) / 256; ++i) {
        const int idx = tid + i * 256;
        if (idx < M * CH) {
            const int row = idx / CH;
            const int c = idx - row * CH;
            *(short8*)&lds[(size_t)(row * CH + (c ^ (row & 7))) * 8] =
                *(const short8*)(BT + (size_t)row * K + c * 8);
        }
    }
    __syncthreads();

    const int wave = tid >> 6;
    const int lane = tid & 63;
    const int l15 = lane & 15;
    const int quad = lane >> 4;
    const int rowbase = blockIdx.x * 128 + wave * 32;
    const int r0 = min(rowbase + l15, n - 1);
    const int r1 = min(rowbase + 16 + l15, n - 1);
    const size_t off0 = (size_t)r0 * K + quad * 8;
    const size_t off1 = (size_t)r1 * K + quad * 8;

    fx4 acc[2][TILES];
#pragma unroll
    for (int rp = 0; rp < 2; ++rp)
#pragma unroll
        for (int t = 0; t < TILES; ++t) acc[rp][t] = (fx4){0.f, 0.f, 0.f, 0.f};

    fx4 c0a, c0b, c1a, c1b, n0a, n0b, n1a, n1b;
    short8 cb0, cb1, nb0, nb1;

    if constexpr (A_F32) {
        const float* A = (const float*)Avoid;
        c0a = *(const fx4*)(A + off0);
        c0b = *(const fx4*)(A + off0 + 4);
        c1a = *(const fx4*)(A + off1);
        c1b = *(const fx4*)(A + off1 + 4);
    } else {
        const ushort_t* A = (const ushort_t*)Avoid;
        cb0 = *(const short8*)(A + off0);
        cb1 = *(const short8*)(A + off1);
    }

#pragma unroll
    for (int kc = 0; kc < NC; ++kc) {
        if (kc + 1 < NC) {
            const int kd = (kc + 1) * 32;
            if constexpr (A_F32) {
                const float* A = (const float*)Avoid;
                n0a = *(const fx4*)(A + off0 + kd);
                n0b = *(const fx4*)(A + off0 + kd + 4);
                n1a = *(const fx4*)(A + off1 + kd);
                n1b = *(const fx4*)(A + off1 + kd + 4);
            } else {
                const ushort_t* A = (const ushort_t*)Avoid;
                nb0 = *(const short8*)(A + off0 + kd);
                nb1 = *(const short8*)(A + off1 + kd);
            }
        }
        short8 bf[TILES];
#pragma unroll
        for (int t = 0; t < TILES; ++t) {
            const int brow = t * 16 + l15;
            const int c = kc * 4 + quad;
            bf[t] = *(const short8*)&lds[(size_t)(brow * CH +
                                                  (c ^ (brow & 7))) * 8];
        }
        short8 af0, af1;
        if constexpr (A_F32) {
            union { short8 v; ushort_t u[8]; } u0, u1;
#pragma unroll
            for (int j = 0; j < 4; ++j) {
                u0.u[j] = f32_to_bf16(c0a[j]);
                u0.u[4 + j] = f32_to_bf16(c0b[j]);
                u1.u[j] = f32_to_bf16(c1a[j]);
                u1.u[4 + j] = f32_to_bf16(c1b[j]);
            }
            af0 = u0.v;
            af1 = u1.v;
        } else {
            af0 = cb0;
            af1 = cb1;
        }
#pragma unroll
        for (int t = 0; t < TILES; ++t) {
            acc[0][t] = __builtin_amdgcn_mfma_f32_16x16x32_bf16(af0, bf[t],
                                                                acc[0][t],
                                                                0, 0, 0);
            acc[1][t] = __builtin_amdgcn_mfma_f32_16x16x32_bf16(af1, bf[t],
                                                                acc[1][t],
                                                                0, 0, 0);
        }
        if (kc + 1 < NC) {
            if constexpr (A_F32) {
                c0a = n0a; c0b = n0b; c1a = n1a; c1b = n1b;
            } else {
                cb0 = nb0; cb1 = nb1;
            }
        }
    }

#pragma unroll
    for (int rp = 0; rp < 2; ++rp) {
        const int crow0 = rowbase + rp * 16 + quad * 4;
#pragma unroll
        for (int t = 0; t < TILES; ++t) {
#pragma unroll
            for (int r = 0; r < 4; ++r) {
                const int rr = crow0 + r;
                if (rr < n)
                    C[(size_t)rr * M + t * 16 + l15] =
                        f32_to_bf16(acc[rp][t][r]);
            }
        }
    }
}

// ------------- per-node attention coefficients a_src, a_dst ---------------
template <int H, int C>
__global__ void att_kernel(const ushort_t* __restrict__ h,
                           const float* __restrict__ att_s,
                           const float* __restrict__ att_d,
                           float* __restrict__ as_, float* __restrict__ ad_,
                           int n) {
    const int idx = blockIdx.x * blockDim.x + threadIdx.x;
    if (idx >= n * H) return;
    const int node = idx / H;
    const int hh = idx % H;
    const ushort_t* hp = h + (size_t)node * H * C + hh * C;
    float s0 = 0.f, s1 = 0.f;
#pragma unroll
    for (int c = 0; c < C; ++c) {
        const float v = bf16_to_f32(hp[c]);
        s0 += v * att_s[hh * C + c];
        s1 += v * att_d[hh * C + c];
    }
    as_[idx] = s0;
    ad_[idx] = s1;
}

// ------------------- CSR build via binned counting sort -------------------
__global__ __launch_bounds__(1024) void hist_kernel(const int* __restrict__ dst,
                                                    int* __restrict__ histG,
                                                    int e, int chunk, int NB,
                                                    int G) {
    __shared__ int hl[512];
    for (int b = threadIdx.x; b < NB; b += 1024) hl[b] = 0;
    __syncthreads();
    const int g = blockIdx.x;
    const int lo = g * chunk;
    const int hi = min(lo + chunk, e);
    for (int i = lo + threadIdx.x; i < hi; i += 1024)
        atomicAdd(&hl[dst[i] >> 8], 1);
    __syncthreads();
    for (int b = threadIdx.x; b < NB; b += 1024) histG[b * G + g] = hl[b];
}

__global__ __launch_bounds__(1024) void scan1_kernel(const int* __restrict__ in,
                                                     int* __restrict__ out,
                                                     int* __restrict__ sums,
                                                     int n) {
    __shared__ int s[1024];
    const int t = threadIdx.x;
    const int i = blockIdx.x * 1024 + t;
    const int v = (i < n) ? in[i] : 0;
    s[t] = v;
    __syncthreads();
    for (int d = 1; d < 1024; d <<= 1) {
        const int x = (t >= d) ? s[t - d] : 0;
        __syncthreads();
        s[t] += x;
        __syncthreads();
    }
    if (i < n) out[i] = s[t] - v;
    if (t == 1023) sums[blockIdx.x] = s[1023];
}

__global__ __launch_bounds__(128) void scan2_kernel(int* sums, int nb) {
    __shared__ int s[128];
    const int t = threadIdx.x;
    const int v = (t < nb) ? sums[t] : 0;
    s[t] = v;
    __syncthreads();
    for (int d = 1; d < 128; d <<= 1) {
        const int x = (t >= d) ? s[t - d] : 0;
        __syncthreads();
        s[t] += x;
        __syncthreads();
    }
    if (t < nb) sums[t] = s[t] - v;
}

__global__ __launch_bounds__(1024) void scan3_kernel(int* __restrict__ out,
                                                     const int* __restrict__ sums,
                                                     int n) {
    const int i = blockIdx.x * 1024 + threadIdx.x;
    if (i < n) out[i] += sums[blockIdx.x];
}

__global__ __launch_bounds__(1024) void bin_kernel(const int* __restrict__ src,
                                                   const int* __restrict__ dst,
                                                   const int* __restrict__ base,
                                                   int2* __restrict__ binned,
                                                   int e, int chunk, int NB,
                                                   int G) {
    __shared__ int cur[512];
    const int g = blockIdx.x;
    for (int b = threadIdx.x; b < NB; b += 1024) cur[b] = base[b * G + g];
    __syncthreads();
    const int lo = g * chunk;
    const int hi = min(lo + chunk, e);
    for (int i = lo + threadIdx.x; i < hi; i += 1024) {
        const int d = dst[i];
        const int p = atomicAdd(&cur[d >> 8], 1);
        binned[p] = make_int2(src[i], d);
    }
}

#define BUILD_CAP 6144
__global__ __launch_bounds__(256) void build_kernel(
    const int2* __restrict__ binned, const int* __restrict__ base,
    int* __restrict__ csr, int* __restrict__ deg, int* __restrict__ offs,
    int e, int n, int NB, int G) {
    __shared__ int2 ep[BUILD_CAP];
    __shared__ int degL[256];
    __shared__ int offL[256];
    __shared__ int curL[256];
    const int b = blockIdx.x;
    const int tid = threadIdx.x;
    const int start = base[b * G];
    const int end = (b == NB - 1) ? e : base[(b + 1) * G];
    const int cnt = end - start;
    const bool stage = (cnt <= BUILD_CAP);
    degL[tid] = 0;
    if (stage)
        for (int i = tid; i < cnt; i += 256) ep[i] = binned[start + i];
    __syncthreads();
    if (stage) {
        for (int i = tid; i < cnt; i += 256) atomicAdd(&degL[ep[i].y & 255], 1);
    } else {
        for (int i = tid; i < cnt; i += 256)
            atomicAdd(&degL[binned[start + i].y & 255], 1);
    }
    __syncthreads();
    const int v = degL[tid];
    offL[tid] = v;
    __syncthreads();
    for (int d = 1; d < 256; d <<= 1) {
        const int x = (tid >= d) ? offL[tid - d] : 0;
        __syncthreads();
        offL[tid] += x;
        __syncthreads();
    }
    const int excl = offL[tid] - v;
    curL[tid] = excl;
    const int node = (b << 8) + tid;
    if (node < n) {
        deg[node] = v;
        offs[node] = start + excl;
    }
    __syncthreads();
    if (stage) {
        for (int i = tid; i < cnt; i += 256) {
            const int p = atomicAdd(&curL[ep[i].y & 255], 1);
            csr[start + p] = ep[i].x;
        }
    } else {
        for (int i = tid; i < cnt; i += 256) {
            const int2 pr = binned[start + i];
            const int p = atomicAdd(&curL[pr.y & 255], 1);
            csr[start + p] = pr.x;
        }
    }
}

// --------- single-pass gather-aggregate + fused softmax denominator -------
// One wave (64 threads) per node: independent retirement, no workgroup
// load-imbalance. Per-lane VECTOR loads throughout (fine-grained vmcnt
// pipelining; SMEM s_load chains serialize via lgkmcnt(0) -- round-2
// lesson). Explicit 2-deep software pipeline with named A/B buffers
// (static indexing; rule #20); tail chunk is index-clamped + p-masked so
// there is no serial remainder loop.
template <int H, int C, bool DO_ELU, bool OUT_BF16>
__global__ __launch_bounds__(64) void agg_kernel(
    const ushort_t* __restrict__ h, const float* __restrict__ a_src,
    const float* __restrict__ a_dst, const int* __restrict__ csr,
    const int* __restrict__ offs, const int* __restrict__ deg,
    const float* __restrict__ bias, void* __restrict__ outv, int n) {
    constexpr int HC = H * C;
    constexpr int R = HC / 64;  // 2 (layer1) or 1 (layer2)
    constexpr int U = 8;        // edge chunk size
    const int dst = blockIdx.x;
    const int lane = threadIdx.x;
    const int start = offs[dst];
    const int d = deg[dst];
    const int myh = lane & (H - 1);
    const int ch0 = lane * R;
    const int hh = ch0 / C;
    const float advm = a_dst[dst * H + myh];
    float acc0 = 0.f, acc1 = 0.f;
    float L = 0.f;

    // ---- self-loop term ----
    {
        float e = a_src[dst * H + myh] + advm;
        e = fmaxf(e, 0.2f * e);
        const float p = __expf(e);
        L += p;
        const float a = (H > 1) ? __shfl(p, hh) : p;
        const ushort_t* hp = h + (size_t)dst * HC + ch0;
        if (R == 2) {
            const uint_t v = *(const uint_t*)hp;
            acc0 += a * bf16_to_f32((ushort_t)(v & 0xffffu));
            acc1 += a * bf16_to_f32((ushort_t)(v >> 16));
        } else {
            acc0 += a * bf16_to_f32(hp[0]);
        }
    }

    const int nc = (d + U - 1) / U;  // masked chunks (incl. partial tail)
    const int dm1 = (d > 0) ? d - 1 : 0;

// stage chunk cc: csr -> a_src & h gathers (all per-lane vector loads,
// vmcnt-pipelined) -> precompute masked p.
#define STAGE(cc, pX, hX)                                                   \
    {                                                                       \
        int sv_[U];                                                         \
        _Pragma("unroll") for (int u = 0; u < U; ++u)                       \
            sv_[u] = csr[start + min((cc) * U + u, dm1)];                   \
        float es_[U];                                                       \
        _Pragma("unroll") for (int u = 0; u < U; ++u)                       \
            es_[u] = a_src[sv_[u] * H + myh];                               \
        _Pragma("unroll") for (int u = 0; u < U; ++u) {                     \
            const ushort_t* hp_ = h + (size_t)sv_[u] * HC + ch0;            \
            if (R == 2) hX[u] = *(const uint_t*)hp_;                        \
            else hX[u] = (uint_t)(*hp_);                                    \
        }                                                                   \
        _Pragma("unroll") for (int u = 0; u < U; ++u) {                     \
            float e_ = es_[u] + advm;                                       \
            e_ = fmaxf(e_, 0.2f * e_);                                      \
            const float p_ = __expf(e_);                                    \
            pX[u] = ((cc) * U + u < d) ? p_ : 0.f;                          \
        }                                                                   \
    }

#define ACCUM(pX, hX)                                                      \
    _Pragma("unroll") for (int u = 0; u < U; ++u) {                        \
        L += pX[u];                                                        \
        const float a_ = (H > 1) ? __shfl(pX[u], hh) : pX[u];              \
        if (R == 2) {                                                      \
            acc0 += a_ * bf16_to_f32((ushort_t)(hX[u] & 0xffffu));         \
            acc1 += a_ * bf16_to_f32((ushort_t)(hX[u] >> 16));             \
        } else {                                                           \
            acc0 += a_ * bf16_to_f32((ushort_t)hX[u]);                     \
        }                                                                  \
    }

    float pA[U], pB[U];
    uint_t hA[U], hB[U];
    if (nc > 0) {
        STAGE(0, pA, hA);
        if (nc > 1) STAGE(1, pB, hB);
        for (int c = 0; c < nc; c += 2) {
            ACCUM(pA, hA);
            if (c + 2 < nc) STAGE(c + 2, pA, hA);
            if (c + 1 < nc) ACCUM(pB, hB);
            if (c + 3 < nc) STAGE(c + 3, pB, hB);
        }
    }
#undef STAGE
#undef ACCUM

    const float Ld = (H > 1) ? __shfl(L, hh) : L;
    const float linv = 1.f / (Ld + 1e-16f);
    float r0 = acc0 * linv + bias[ch0];
    if (DO_ELU) r0 = (r0 > 0.f) ? r0 : (__expf(r0) - 1.f);
    if (R == 2) {
        float r1 = acc1 * linv + bias[ch0 + 1];
        if (DO_ELU) r1 = (r1 > 0.f) ? r1 : (__expf(r1) - 1.f);
        if (OUT_BF16) {
            const uint_t packed =
                (uint_t)f32_to_bf16(r0) | ((uint_t)f32_to_bf16(r1) << 16);
            *(uint_t*)((ushort_t*)outv + (size_t)dst * HC + ch0) = packed;
        } else {
            *(float2*)((float*)outv + (size_t)dst * HC + ch0) =
                make_float2(r0, r1);
        }
    } else {
        if (OUT_BF16)
            ((ushort_t*)outv)[(size_t)dst * HC + ch0] = f32_to_bf16(r0);
        else
            ((float*)outv)[(size_t)dst * HC + ch0] = r0;
    }
}

// --------------------------------------------------------------------------
extern "C" void kernel_launch(void* const* d_in, const int* in_sizes, int n_in,
                              void* d_out, int out_size, void* d_ws,
                              size_t ws_size, hipStream_t stream) {
    const float* x = (const float*)d_in[0];
    const int* ei = (const int*)d_in[1];
    const float* W1 = (const float*)d_in[2];
    const float* att_s1 = (const float*)d_in[3];
    const float* att_d1 = (const float*)d_in[4];
    const float* b1 = (const float*)d_in[5];
    const float* W2 = (const float*)d_in[6];
    const float* att_s2 = (const float*)d_in[7];
    const float* att_d2 = (const float*)d_in[8];
    const float* b2 = (const float*)d_in[9];

    const int N = in_sizes[0] / 256;  // 100000
    const int E = in_sizes[1] / 2;    // 1600000
    const int* srcp = ei;
    const int* dstp = ei + E;

    const int NB = (N + 255) >> 8;  // 391 buckets of 256 nodes
    const int G = 128;
    const int NBG = NB * G;
    const int chunk = (E + G - 1) / G;
    const int nbs = (NBG + 1023) / 1024;

    // workspace layout
    float* as1 = (float*)d_ws;           // N*4
    float* ad1 = as1 + (size_t)N * 4;    // N*4
    float* as2 = ad1 + (size_t)N * 4;    // N
    float* ad2 = as2 + N;                // N
    int* histG = (int*)(ad2 + N);        // NBG
    int* base = histG + NBG;             // NBG
    int* sums = base + NBG;              // 128
    int* deg = sums + 128;               // N
    int* offs = deg + N;                 // N
    int* csr = offs + N;                 // E
    int2* binned = (int2*)(csr + E);     // E pairs (dead after build)
    ushort_t* h1 = (ushort_t*)binned;    // N*128 bf16 (overlays binned)
    ushort_t* h2 = h1 + (size_t)N * 128; // N*64 bf16
    ushort_t* h1p = h2 + (size_t)N * 64; // N*128 bf16 (agg1 out, gemm2 A)
    ushort_t* W1T = h1p + (size_t)N * 128;  // 128*256
    ushort_t* W2T = W1T + 128 * 256;        // 64*128

    // ---- weight transpose + bf16 convert ----
    convT_kernel<<<(256 * 128 + 255) / 256, 256, 0, stream>>>(W1, W1T, 256, 128);
    convT_kernel<<<(128 * 64 + 255) / 256, 256, 0, stream>>>(W2, W2T, 128, 64);

    // ---- CSR build (binned counting sort, no global atomics) ----
    hist_kernel<<<G, 1024, 0, stream>>>(dstp, histG, E, chunk, NB, G);
    scan1_kernel<<<nbs, 1024, 0, stream>>>(histG, base, sums, NBG);
    scan2_kernel<<<1, 128, 0, stream>>>(sums, nbs);
    scan3_kernel<<<nbs, 1024, 0, stream>>>(base, sums, NBG);
    bin_kernel<<<G, 1024, 0, stream>>>(srcp, dstp, base, binned, E, chunk, NB,
                                       G);
    build_kernel<<<NB, 256, 0, stream>>>(binned, base, csr, deg, offs, E, N,
                                         NB, G);

    const int gblk = (N + 127) / 128;  // 782 (128 rows per block)

    // ---- layer 1 ----
    gemm_lds_kernel<8, true, 256><<<gblk, 256, 0, stream>>>(x, W1T, h1, N);
    att_kernel<4, 32><<<(N * 4 + 255) / 256, 256, 0, stream>>>(h1, att_s1,
                                                               att_d1, as1,
                                                               ad1, N);
    agg_kernel<4, 32, true, true><<<N, 64, 0, stream>>>(h1, as1, ad1, csr,
                                                        offs, deg, b1, h1p, N);

    // ---- layer 2 ----
    gemm_lds_kernel<4, false, 128><<<gblk, 256, 0, stream>>>(h1p, W2T, h2, N);
    att_kernel<1, 64><<<(N + 255) / 256, 256, 0, stream>>>(h2, att_s2, att_d2,
                                                           as2, ad2, N);
    agg_kernel<1, 64, false, false><<<N, 64, 0, stream>>>(h2, as2, ad2, csr,
                                                          offs, deg, b2, d_out,
                                                          N);
}

// Round 4
// 409.462 us; speedup vs baseline: 1.2134x; 1.0723x over previous
//
#include <hip/hip_runtime.h>
#include <math.h>

typedef unsigned short ushort_t;
typedef unsigned int uint_t;
typedef __attribute__((ext_vector_type(8))) short short8;
typedef __attribute__((ext_vector_type(4))) float fx4;

__device__ __forceinline__ float bf16_to_f32(ushort_t u) {
    union { uint_t i; float f; } c;
    c.i = ((uint_t)u) << 16;
    return c.f;
}
__device__ __forceinline__ ushort_t f32_to_bf16(float f) {
    union { float f; uint_t i; } c;
    c.f = f;
    const uint_t x = c.i;
    return (ushort_t)((x + 0x7fffu + ((x >> 16) & 1u)) >> 16);
}

// ---- W transpose + bf16 convert: WT[m][k] = bf16(W[k][m]) ----------------
__global__ void convT_kernel(const float* __restrict__ W,
                             ushort_t* __restrict__ WT, int k, int m) {
    const int idx = blockIdx.x * 256 + threadIdx.x;
    if (idx >= k * m) return;
    const int mm = idx / k;
    const int kk = idx % k;
    WT[idx] = f32_to_bf16(W[(size_t)kk * m + mm]);
}

// ---- MFMA GEMM with B staged in LDS ---------------------------------------
// C[n][TILES*16](bf16) = A[n][K] * B[K][TILES*16], BT[col][K] bf16.
// 4 waves/block, each wave owns 2 row-tiles (32 rows) -> block = 128 rows.
// BT staged in LDS once, XOR-swizzled on 16B chunks (c ^ (row&7)).
// A is register double-buffered: prefetch kc+1 while MFMAing kc.
template <int TILES, bool A_F32, int K>
__global__ __launch_bounds__(256) void gemm_lds_kernel(
    const void* __restrict__ Avoid, const ushort_t* __restrict__ BT,
    ushort_t* __restrict__ C, int n) {
    constexpr int M = TILES * 16;
    constexpr int CH = K / 8;  // 16B chunks per B row
    constexpr int NC = K / 32; // K-chunks
    __shared__ ushort_t lds[M * K];  // 64KB (layer1) / 16KB (layer2)
    const int tid = threadIdx.x;

    // ---- stage BT -> LDS, swizzled ----
#pragma unroll
    for (int i = 0; i < (M * CH + 255) / 256; ++i) {
        const int idx = tid + i * 256;
        if (idx < M * CH) {
            const int row = idx / CH;
            const int c = idx - row * CH;
            *(short8*)&lds[(size_t)(row * CH + (c ^ (row & 7))) * 8] =
                *(const short8*)(BT + (size_t)row * K + c * 8);
        }
    }
    __syncthreads();

    const int wave = tid >> 6;
    const int lane = tid & 63;
    const int l15 = lane & 15;
    const int quad = lane >> 4;
    const int rowbase = blockIdx.x * 128 + wave * 32;
    const int r0 = min(rowbase + l15, n - 1);
    const int r1 = min(rowbase + 16 + l15, n - 1);
    const size_t off0 = (size_t)r0 * K + quad * 8;
    const size_t off1 = (size_t)r1 * K + quad * 8;

    fx4 acc[2][TILES];
#pragma unroll
    for (int rp = 0; rp < 2; ++rp)
#pragma unroll
        for (int t = 0; t < TILES; ++t) acc[rp][t] = (fx4){0.f, 0.f, 0.f, 0.f};

    fx4 c0a, c0b, c1a, c1b, n0a, n0b, n1a, n1b;
    short8 cb0, cb1, nb0, nb1;

    if constexpr (A_F32) {
        const float* A = (const float*)Avoid;
        c0a = *(const fx4*)(A + off0);
        c0b = *(const fx4*)(A + off0 + 4);
        c1a = *(const fx4*)(A + off1);
        c1b = *(const fx4*)(A + off1 + 4);
    } else {
        const ushort_t* A = (const ushort_t*)Avoid;
        cb0 = *(const short8*)(A + off0);
        cb1 = *(const short8*)(A + off1);
    }

#pragma unroll
    for (int kc = 0; kc < NC; ++kc) {
        if (kc + 1 < NC) {
            const int kd = (kc + 1) * 32;
            if constexpr (A_F32) {
                const float* A = (const float*)Avoid;
                n0a = *(const fx4*)(A + off0 + kd);
                n0b = *(const fx4*)(A + off0 + kd + 4);
                n1a = *(const fx4*)(A + off1 + kd);
                n1b = *(const fx4*)(A + off1 + kd + 4);
            } else {
                const ushort_t* A = (const ushort_t*)Avoid;
                nb0 = *(const short8*)(A + off0 + kd);
                nb1 = *(const short8*)(A + off1 + kd);
            }
        }
        short8 bf[TILES];
#pragma unroll
        for (int t = 0; t < TILES; ++t) {
            const int brow = t * 16 + l15;
            const int c = kc * 4 + quad;
            bf[t] = *(const short8*)&lds[(size_t)(brow * CH +
                                                  (c ^ (brow & 7))) * 8];
        }
        short8 af0, af1;
        if constexpr (A_F32) {
            union { short8 v; ushort_t u[8]; } u0, u1;
#pragma unroll
            for (int j = 0; j < 4; ++j) {
                u0.u[j] = f32_to_bf16(c0a[j]);
                u0.u[4 + j] = f32_to_bf16(c0b[j]);
                u1.u[j] = f32_to_bf16(c1a[j]);
                u1.u[4 + j] = f32_to_bf16(c1b[j]);
            }
            af0 = u0.v;
            af1 = u1.v;
        } else {
            af0 = cb0;
            af1 = cb1;
        }
#pragma unroll
        for (int t = 0; t < TILES; ++t) {
            acc[0][t] = __builtin_amdgcn_mfma_f32_16x16x32_bf16(af0, bf[t],
                                                                acc[0][t],
                                                                0, 0, 0);
            acc[1][t] = __builtin_amdgcn_mfma_f32_16x16x32_bf16(af1, bf[t],
                                                                acc[1][t],
                                                                0, 0, 0);
        }
        if (kc + 1 < NC) {
            if constexpr (A_F32) {
                c0a = n0a; c0b = n0b; c1a = n1a; c1b = n1b;
            } else {
                cb0 = nb0; cb1 = nb1;
            }
        }
    }

#pragma unroll
    for (int rp = 0; rp < 2; ++rp) {
        const int crow0 = rowbase + rp * 16 + quad * 4;
#pragma unroll
        for (int t = 0; t < TILES; ++t) {
#pragma unroll
            for (int r = 0; r < 4; ++r) {
                const int rr = crow0 + r;
                if (rr < n)
                    C[(size_t)rr * M + t * 16 + l15] =
                        f32_to_bf16(acc[rp][t][r]);
            }
        }
    }
}

// ------------- per-node attention coefficients a_src, a_dst ---------------
template <int H, int C>
__global__ void att_kernel(const ushort_t* __restrict__ h,
                           const float* __restrict__ att_s,
                           const float* __restrict__ att_d,
                           float* __restrict__ as_, float* __restrict__ ad_,
                           int n) {
    const int idx = blockIdx.x * blockDim.x + threadIdx.x;
    if (idx >= n * H) return;
    const int node = idx / H;
    const int hh = idx % H;
    const ushort_t* hp = h + (size_t)node * H * C + hh * C;
    float s0 = 0.f, s1 = 0.f;
#pragma unroll
    for (int c = 0; c < C; ++c) {
        const float v = bf16_to_f32(hp[c]);
        s0 += v * att_s[hh * C + c];
        s1 += v * att_d[hh * C + c];
    }
    as_[idx] = s0;
    ad_[idx] = s1;
}

// ------------------- CSR build via binned counting sort -------------------
__global__ __launch_bounds__(1024) void hist_kernel(const int* __restrict__ dst,
                                                    int* __restrict__ histG,
                                                    int e, int chunk, int NB,
                                                    int G) {
    __shared__ int hl[512];
    for (int b = threadIdx.x; b < NB; b += 1024) hl[b] = 0;
    __syncthreads();
    const int g = blockIdx.x;
    const int lo = g * chunk;
    const int hi = min(lo + chunk, e);
    for (int i = lo + threadIdx.x; i < hi; i += 1024)
        atomicAdd(&hl[dst[i] >> 8], 1);
    __syncthreads();
    for (int b = threadIdx.x; b < NB; b += 1024) histG[b * G + g] = hl[b];
}

__global__ __launch_bounds__(1024) void scan1_kernel(const int* __restrict__ in,
                                                     int* __restrict__ out,
                                                     int* __restrict__ sums,
                                                     int n) {
    __shared__ int s[1024];
    const int t = threadIdx.x;
    const int i = blockIdx.x * 1024 + t;
    const int v = (i < n) ? in[i] : 0;
    s[t] = v;
    __syncthreads();
    for (int d = 1; d < 1024; d <<= 1) {
        const int x = (t >= d) ? s[t - d] : 0;
        __syncthreads();
        s[t] += x;
        __syncthreads();
    }
    if (i < n) out[i] = s[t] - v;
    if (t == 1023) sums[blockIdx.x] = s[1023];
}

__global__ __launch_bounds__(128) void scan2_kernel(int* sums, int nb) {
    __shared__ int s[128];
    const int t = threadIdx.x;
    const int v = (t < nb) ? sums[t] : 0;
    s[t] = v;
    __syncthreads();
    for (int d = 1; d < 128; d <<= 1) {
        const int x = (t >= d) ? s[t - d] : 0;
        __syncthreads();
        s[t] += x;
        __syncthreads();
    }
    if (t < nb) sums[t] = s[t] - v;
}

__global__ __launch_bounds__(1024) void scan3_kernel(int* __restrict__ out,
                                                     const int* __restrict__ sums,
                                                     int n) {
    const int i = blockIdx.x * 1024 + threadIdx.x;
    if (i < n) out[i] += sums[blockIdx.x];
}

__global__ __launch_bounds__(1024) void bin_kernel(const int* __restrict__ src,
                                                   const int* __restrict__ dst,
                                                   const int* __restrict__ base,
                                                   int2* __restrict__ binned,
                                                   int e, int chunk, int NB,
                                                   int G) {
    __shared__ int cur[512];
    const int g = blockIdx.x;
    for (int b = threadIdx.x; b < NB; b += 1024) cur[b] = base[b * G + g];
    __syncthreads();
    const int lo = g * chunk;
    const int hi = min(lo + chunk, e);
    for (int i = lo + threadIdx.x; i < hi; i += 1024) {
        const int d = dst[i];
        const int p = atomicAdd(&cur[d >> 8], 1);
        binned[p] = make_int2(src[i], d);
    }
}

#define BUILD_CAP 6144
__global__ __launch_bounds__(256) void build_kernel(
    const int2* __restrict__ binned, const int* __restrict__ base,
    int* __restrict__ csr, int* __restrict__ deg, int* __restrict__ offs,
    int e, int n, int NB, int G) {
    __shared__ int2 ep[BUILD_CAP];
    __shared__ int degL[256];
    __shared__ int offL[256];
    __shared__ int curL[256];
    const int b = blockIdx.x;
    const int tid = threadIdx.x;
    const int start = base[b * G];
    const int end = (b == NB - 1) ? e : base[(b + 1) * G];
    const int cnt = end - start;
    const bool stage = (cnt <= BUILD_CAP);
    degL[tid] = 0;
    if (stage)
        for (int i = tid; i < cnt; i += 256) ep[i] = binned[start + i];
    __syncthreads();
    if (stage) {
        for (int i = tid; i < cnt; i += 256) atomicAdd(&degL[ep[i].y & 255], 1);
    } else {
        for (int i = tid; i < cnt; i += 256)
            atomicAdd(&degL[binned[start + i].y & 255], 1);
    }
    __syncthreads();
    const int v = degL[tid];
    offL[tid] = v;
    __syncthreads();
    for (int d = 1; d < 256; d <<= 1) {
        const int x = (tid >= d) ? offL[tid - d] : 0;
        __syncthreads();
        offL[tid] += x;
        __syncthreads();
    }
    const int excl = offL[tid] - v;
    curL[tid] = excl;
    const int node = (b << 8) + tid;
    if (node < n) {
        deg[node] = v;
        offs[node] = start + excl;
    }
    __syncthreads();
    if (stage) {
        for (int i = tid; i < cnt; i += 256) {
            const int p = atomicAdd(&curL[ep[i].y & 255], 1);
            csr[start + p] = ep[i].x;
        }
    } else {
        for (int i = tid; i < cnt; i += 256) {
            const int2 pr = binned[start + i];
            const int p = atomicAdd(&curL[pr.y & 255], 1);
            csr[start + p] = pr.x;
        }
    }
}

// --------- single-pass gather-aggregate + fused softmax denominator -------
// One wave per node; round-1 loop structure (the compiler pipelines the
// U=8 batched loads fine; explicit A/B pipelining regressed -- round 3).
// VALU-trim vs round 1:
//  * myh == hh: each lane computes exactly the softmax term of the head it
//    accumulates -> no per-edge __shfl and no final __shfl (same 16B
//    a_src line per edge, just a lane-permuted mapping; numerically
//    identical).
//  * h-row gather uses a readfirstlane SGPR base (src is wave-uniform):
//    SALU address math + VMEM saddr load, keeping vmcnt pipelining
//    (round-2 lesson applies to s_load DATA chains, not SGPR-base vector
//    loads). csr/a_src keep per-lane form so nothing new scalarizes.
template <int H, int C, bool DO_ELU, bool OUT_BF16>
__global__ __launch_bounds__(64) void agg_kernel(
    const ushort_t* __restrict__ h, const float* __restrict__ a_src,
    const float* __restrict__ a_dst, const int* __restrict__ csr,
    const int* __restrict__ offs, const int* __restrict__ deg,
    const float* __restrict__ bias, void* __restrict__ outv, int n) {
    constexpr int HC = H * C;
    constexpr int R = HC / 64;  // 2 (layer1) or 1 (layer2)
    constexpr int U = 8;        // edge chunk size
    const int dst = blockIdx.x;
    const int lane = threadIdx.x;
    const int start = offs[dst];
    const int d = deg[dst];
    const int ch0 = lane * R;
    const int hh = ch0 / C;   // head this lane accumulates
    const int myh = hh;       // same head -> shuffle-free softmax
    const float advm = a_dst[dst * H + myh];
    float acc0 = 0.f, acc1 = 0.f;
    float L = 0.f;

    // ---- self-loop term ----
    {
        float e = a_src[dst * H + myh] + advm;
        e = fmaxf(e, 0.2f * e);
        const float p = __expf(e);
        L += p;
        const ushort_t* hp = h + (size_t)dst * HC + ch0;
        if (R == 2) {
            const uint_t v = *(const uint_t*)hp;
            acc0 += p * bf16_to_f32((ushort_t)(v & 0xffffu));
            acc1 += p * bf16_to_f32((ushort_t)(v >> 16));
        } else {
            acc0 += p * bf16_to_f32(hp[0]);
        }
    }

    int j = 0;
    for (; j + U <= d; j += U) {
        int sv[U];
#pragma unroll
        for (int u = 0; u < U; ++u) sv[u] = csr[start + j + u];
        int ss[U];
#pragma unroll
        for (int u = 0; u < U; ++u)
            ss[u] = __builtin_amdgcn_readfirstlane(sv[u]);
        float es[U];
#pragma unroll
        for (int u = 0; u < U; ++u) es[u] = a_src[sv[u] * H + myh];
        uint_t hv[U];
#pragma unroll
        for (int u = 0; u < U; ++u) {
            const ushort_t* hp = h + (size_t)ss[u] * HC + ch0;
            if (R == 2) hv[u] = *(const uint_t*)hp;
            else hv[u] = (uint_t)(*hp);
        }
#pragma unroll
        for (int u = 0; u < U; ++u) {
            float e = es[u] + advm;
            e = fmaxf(e, 0.2f * e);
            const float p = __expf(e);
            L += p;
            if (R == 2) {
                acc0 += p * bf16_to_f32((ushort_t)(hv[u] & 0xffffu));
                acc1 += p * bf16_to_f32((ushort_t)(hv[u] >> 16));
            } else {
                acc0 += p * bf16_to_f32((ushort_t)hv[u]);
            }
        }
    }
    for (; j < d; ++j) {
        const int sv = csr[start + j];
        const int ss = __builtin_amdgcn_readfirstlane(sv);
        float e = a_src[sv * H + myh] + advm;
        e = fmaxf(e, 0.2f * e);
        const float p = __expf(e);
        L += p;
        const ushort_t* hp = h + (size_t)ss * HC + ch0;
        if (R == 2) {
            const uint_t v = *(const uint_t*)hp;
            acc0 += p * bf16_to_f32((ushort_t)(v & 0xffffu));
            acc1 += p * bf16_to_f32((ushort_t)(v >> 16));
        } else {
            acc0 += p * bf16_to_f32(hp[0]);
        }
    }

    const float linv = 1.f / (L + 1e-16f);
    float r0 = acc0 * linv + bias[ch0];
    if (DO_ELU) r0 = (r0 > 0.f) ? r0 : (__expf(r0) - 1.f);
    if (R == 2) {
        float r1 = acc1 * linv + bias[ch0 + 1];
        if (DO_ELU) r1 = (r1 > 0.f) ? r1 : (__expf(r1) - 1.f);
        if (OUT_BF16) {
            const uint_t packed =
                (uint_t)f32_to_bf16(r0) | ((uint_t)f32_to_bf16(r1) << 16);
            *(uint_t*)((ushort_t*)outv + (size_t)dst * HC + ch0) = packed;
        } else {
            *(float2*)((float*)outv + (size_t)dst * HC + ch0) =
                make_float2(r0, r1);
        }
    } else {
        if (OUT_BF16)
            ((ushort_t*)outv)[(size_t)dst * HC + ch0] = f32_to_bf16(r0);
        else
            ((float*)outv)[(size_t)dst * HC + ch0] = r0;
    }
}

// --------------------------------------------------------------------------
extern "C" void kernel_launch(void* const* d_in, const int* in_sizes, int n_in,
                              void* d_out, int out_size, void* d_ws,
                              size_t ws_size, hipStream_t stream) {
    const float* x = (const float*)d_in[0];
    const int* ei = (const int*)d_in[1];
    const float* W1 = (const float*)d_in[2];
    const float* att_s1 = (const float*)d_in[3];
    const float* att_d1 = (const float*)d_in[4];
    const float* b1 = (const float*)d_in[5];
    const float* W2 = (const float*)d_in[6];
    const float* att_s2 = (const float*)d_in[7];
    const float* att_d2 = (const float*)d_in[8];
    const float* b2 = (const float*)d_in[9];

    const int N = in_sizes[0] / 256;  // 100000
    const int E = in_sizes[1] / 2;    // 1600000
    const int* srcp = ei;
    const int* dstp = ei + E;

    const int NB = (N + 255) >> 8;  // 391 buckets of 256 nodes
    const int G = 128;
    const int NBG = NB * G;
    const int chunk = (E + G - 1) / G;
    const int nbs = (NBG + 1023) / 1024;

    // workspace layout
    float* as1 = (float*)d_ws;           // N*4
    float* ad1 = as1 + (size_t)N * 4;    // N*4
    float* as2 = ad1 + (size_t)N * 4;    // N
    float* ad2 = as2 + N;                // N
    int* histG = (int*)(ad2 + N);        // NBG
    int* base = histG + NBG;             // NBG
    int* sums = base + NBG;              // 128
    int* deg = sums + 128;               // N
    int* offs = deg + N;                 // N
    int* csr = offs + N;                 // E
    int2* binned = (int2*)(csr + E);     // E pairs (dead after build)
    ushort_t* h1 = (ushort_t*)binned;    // N*128 bf16 (overlays binned)
    ushort_t* h2 = h1 + (size_t)N * 128; // N*64 bf16
    ushort_t* h1p = h2 + (size_t)N * 64; // N*128 bf16 (agg1 out, gemm2 A)
    ushort_t* W1T = h1p + (size_t)N * 128;  // 128*256
    ushort_t* W2T = W1T + 128 * 256;        // 64*128

    // ---- weight transpose + bf16 convert ----
    convT_kernel<<<(256 * 128 + 255) / 256, 256, 0, stream>>>(W1, W1T, 256, 128);
    convT_kernel<<<(128 * 64 + 255) / 256, 256, 0, stream>>>(W2, W2T, 128, 64);

    // ---- CSR build (binned counting sort, no global atomics) ----
    hist_kernel<<<G, 1024, 0, stream>>>(dstp, histG, E, chunk, NB, G);
    scan1_kernel<<<nbs, 1024, 0, stream>>>(histG, base, sums, NBG);
    scan2_kernel<<<1, 128, 0, stream>>>(sums, nbs);
    scan3_kernel<<<nbs, 1024, 0, stream>>>(base, sums, NBG);
    bin_kernel<<<G, 1024, 0, stream>>>(srcp, dstp, base, binned, E, chunk, NB,
                                       G);
    build_kernel<<<NB, 256, 0, stream>>>(binned, base, csr, deg, offs, E, N,
                                         NB, G);

    const int gblk = (N + 127) / 128;  // 782 (128 rows per block)

    // ---- layer 1 ----
    gemm_lds_kernel<8, true, 256><<<gblk, 256, 0, stream>>>(x, W1T, h1, N);
    att_kernel<4, 32><<<(N * 4 + 255) / 256, 256, 0, stream>>>(h1, att_s1,
                                                               att_d1, as1,
                                                               ad1, N);
    agg_kernel<4, 32, true, true><<<N, 64, 0, stream>>>(h1, as1, ad1, csr,
                                                        offs, deg, b1, h1p, N);

    // ---- layer 2 ----
    gemm_lds_kernel<4, false, 128><<<gblk, 256, 0, stream>>>(h1p, W2T, h2, N);
    att_kernel<1, 64><<<(N + 255) / 256, 256, 0, stream>>>(h2, att_s2, att_d2,
                                                           as2, ad2, N);
    agg_kernel<1, 64, false, false><<<N, 64, 0, stream>>>(h2, as2, ad2, csr,
                                                          offs, deg, b2, d_out,
                                                          N);
}

// Round 6
// 394.252 us; speedup vs baseline: 1.2602x; 1.0386x over previous
//
#include <hip/hip_runtime.h>
#include <math.h>

typedef unsigned short ushort_t;
typedef unsigned int uint_t;
typedef __attribute__((ext_vector_type(8))) short short8;
typedef __attribute__((ext_vector_type(4))) float fx4;
typedef __attribute__((ext_vector_type(4))) uint_t uintx4;
typedef __attribute__((ext_vector_type(2))) uint_t uintx2;

__device__ __forceinline__ float bf16_to_f32(ushort_t u) {
    union { uint_t i; float f; } c;
    c.i = ((uint_t)u) << 16;
    return c.f;
}
__device__ __forceinline__ ushort_t f32_to_bf16(float f) {
    union { float f; uint_t i; } c;
    c.f = f;
    const uint_t x = c.i;
    return (ushort_t)((x + 0x7fffu + ((x >> 16) & 1u)) >> 16);
}
// unpack one dword (2 bf16) and FMA into two accumulators (2 VALU + 2 FMA)
__device__ __forceinline__ void unpack_fma(uint_t w, float p, float& a0,
                                           float& a1) {
    union { uint_t i; float f; } lo, hi;
    lo.i = w << 16;
    hi.i = w & 0xffff0000u;
    a0 += p * lo.f;
    a1 += p * hi.f;
}

// ---- W transpose + bf16 convert: WT[m][k] = bf16(W[k][m]) ----------------
__global__ void convT_kernel(const float* __restrict__ W,
                             ushort_t* __restrict__ WT, int k, int m) {
    const int idx = blockIdx.x * 256 + threadIdx.x;
    if (idx >= k * m) return;
    const int mm = idx / k;
    const int kk = idx % k;
    WT[idx] = f32_to_bf16(W[(size_t)kk * m + mm]);
}

// ---- MFMA GEMM with B staged in LDS ---------------------------------------
template <int TILES, bool A_F32, int K>
__global__ __launch_bounds__(256) void gemm_lds_kernel(
    const void* __restrict__ Avoid, const ushort_t* __restrict__ BT,
    ushort_t* __restrict__ C, int n) {
    constexpr int M = TILES * 16;
    constexpr int CH = K / 8;  // 16B chunks per B row
    constexpr int NC = K / 32; // K-chunks
    __shared__ ushort_t lds[M * K];  // 64KB (layer1) / 16KB (layer2)
    const int tid = threadIdx.x;

#pragma unroll
    for (int i = 0; i < (M * CH + 255) / 256; ++i) {
        const int idx = tid + i * 256;
        if (idx < M * CH) {
            const int row = idx / CH;
            const int c = idx - row * CH;
            *(short8*)&lds[(size_t)(row * CH + (c ^ (row & 7))) * 8] =
                *(const short8*)(BT + (size_t)row * K + c * 8);
        }
    }
    __syncthreads();

    const int wave = tid >> 6;
    const int lane = tid & 63;
    const int l15 = lane & 15;
    const int quad = lane >> 4;
    const int rowbase = blockIdx.x * 128 + wave * 32;
    const int r0 = min(rowbase + l15, n - 1);
    const int r1 = min(rowbase + 16 + l15, n - 1);
    const size_t off0 = (size_t)r0 * K + quad * 8;
    const size_t off1 = (size_t)r1 * K + quad * 8;

    fx4 acc[2][TILES];
#pragma unroll
    for (int rp = 0; rp < 2; ++rp)
#pragma unroll
        for (int t = 0; t < TILES; ++t) acc[rp][t] = (fx4){0.f, 0.f, 0.f, 0.f};

    fx4 c0a, c0b, c1a, c1b, n0a, n0b, n1a, n1b;
    short8 cb0, cb1, nb0, nb1;

    if constexpr (A_F32) {
        const float* A = (const float*)Avoid;
        c0a = *(const fx4*)(A + off0);
        c0b = *(const fx4*)(A + off0 + 4);
        c1a = *(const fx4*)(A + off1);
        c1b = *(const fx4*)(A + off1 + 4);
    } else {
        const ushort_t* A = (const ushort_t*)Avoid;
        cb0 = *(const short8*)(A + off0);
        cb1 = *(const short8*)(A + off1);
    }

#pragma unroll
    for (int kc = 0; kc < NC; ++kc) {
        if (kc + 1 < NC) {
            const int kd = (kc + 1) * 32;
            if constexpr (A_F32) {
                const float* A = (const float*)Avoid;
                n0a = *(const fx4*)(A + off0 + kd);
                n0b = *(const fx4*)(A + off0 + kd + 4);
                n1a = *(const fx4*)(A + off1 + kd);
                n1b = *(const fx4*)(A + off1 + kd + 4);
            } else {
                const ushort_t* A = (const ushort_t*)Avoid;
                nb0 = *(const short8*)(A + off0 + kd);
                nb1 = *(const short8*)(A + off1 + kd);
            }
        }
        short8 bf[TILES];
#pragma unroll
        for (int t = 0; t < TILES; ++t) {
            const int brow = t * 16 + l15;
            const int c = kc * 4 + quad;
            bf[t] = *(const short8*)&lds[(size_t)(brow * CH +
                                                  (c ^ (brow & 7))) * 8];
        }
        short8 af0, af1;
        if constexpr (A_F32) {
            union { short8 v; ushort_t u[8]; } u0, u1;
#pragma unroll
            for (int j = 0; j < 4; ++j) {
                u0.u[j] = f32_to_bf16(c0a[j]);
                u0.u[4 + j] = f32_to_bf16(c0b[j]);
                u1.u[j] = f32_to_bf16(c1a[j]);
                u1.u[4 + j] = f32_to_bf16(c1b[j]);
            }
            af0 = u0.v;
            af1 = u1.v;
        } else {
            af0 = cb0;
            af1 = cb1;
        }
#pragma unroll
        for (int t = 0; t < TILES; ++t) {
            acc[0][t] = __builtin_amdgcn_mfma_f32_16x16x32_bf16(af0, bf[t],
                                                                acc[0][t],
                                                                0, 0, 0);
            acc[1][t] = __builtin_amdgcn_mfma_f32_16x16x32_bf16(af1, bf[t],
                                                                acc[1][t],
                                                                0, 0, 0);
        }
        if (kc + 1 < NC) {
            if constexpr (A_F32) {
                c0a = n0a; c0b = n0b; c1a = n1a; c1b = n1b;
            } else {
                cb0 = nb0; cb1 = nb1;
            }
        }
    }

#pragma unroll
    for (int rp = 0; rp < 2; ++rp) {
        const int crow0 = rowbase + rp * 16 + quad * 4;
#pragma unroll
        for (int t = 0; t < TILES; ++t) {
#pragma unroll
            for (int r = 0; r < 4; ++r) {
                const int rr = crow0 + r;
                if (rr < n)
                    C[(size_t)rr * M + t * 16 + l15] =
                        f32_to_bf16(acc[rp][t][r]);
            }
        }
    }
}

// ------------- per-node attention coefficients a_src, a_dst ---------------
template <int H, int C>
__global__ void att_kernel(const ushort_t* __restrict__ h,
                           const float* __restrict__ att_s,
                           const float* __restrict__ att_d,
                           float* __restrict__ as_, float* __restrict__ ad_,
                           int n) {
    const int idx = blockIdx.x * blockDim.x + threadIdx.x;
    if (idx >= n * H) return;
    const int node = idx / H;
    const int hh = idx % H;
    const ushort_t* hp = h + (size_t)node * H * C + hh * C;
    float s0 = 0.f, s1 = 0.f;
#pragma unroll
    for (int c = 0; c < C; ++c) {
        const float v = bf16_to_f32(hp[c]);
        s0 += v * att_s[hh * C + c];
        s1 += v * att_d[hh * C + c];
    }
    as_[idx] = s0;
    ad_[idx] = s1;
}

// ------------------- CSR build via binned counting sort -------------------
__global__ __launch_bounds__(1024) void hist_kernel(const int* __restrict__ dst,
                                                    int* __restrict__ histG,
                                                    int e, int chunk, int NB,
                                                    int G) {
    __shared__ int hl[512];
    for (int b = threadIdx.x; b < NB; b += 1024) hl[b] = 0;
    __syncthreads();
    const int g = blockIdx.x;
    const int lo = g * chunk;
    const int hi = min(lo + chunk, e);
    for (int i = lo + threadIdx.x; i < hi; i += 1024)
        atomicAdd(&hl[dst[i] >> 8], 1);
    __syncthreads();
    for (int b = threadIdx.x; b < NB; b += 1024) histG[b * G + g] = hl[b];
}

__global__ __launch_bounds__(1024) void scan1_kernel(const int* __restrict__ in,
                                                     int* __restrict__ out,
                                                     int* __restrict__ sums,
                                                     int n) {
    __shared__ int s[1024];
    const int t = threadIdx.x;
    const int i = blockIdx.x * 1024 + t;
    const int v = (i < n) ? in[i] : 0;
    s[t] = v;
    __syncthreads();
    for (int d = 1; d < 1024; d <<= 1) {
        const int x = (t >= d) ? s[t - d] : 0;
        __syncthreads();
        s[t] += x;
        __syncthreads();
    }
    if (i < n) out[i] = s[t] - v;
    if (t == 1023) sums[blockIdx.x] = s[1023];
}

__global__ __launch_bounds__(128) void scan2_kernel(int* sums, int nb) {
    __shared__ int s[128];
    const int t = threadIdx.x;
    const int v = (t < nb) ? sums[t] : 0;
    s[t] = v;
    __syncthreads();
    for (int d = 1; d < 128; d <<= 1) {
        const int x = (t >= d) ? s[t - d] : 0;
        __syncthreads();
        s[t] += x;
        __syncthreads();
    }
    if (t < nb) sums[t] = s[t] - v;
}

__global__ __launch_bounds__(1024) void scan3_kernel(int* __restrict__ out,
                                                     const int* __restrict__ sums,
                                                     int n) {
    const int i = blockIdx.x * 1024 + threadIdx.x;
    if (i < n) out[i] += sums[blockIdx.x];
}

__global__ __launch_bounds__(1024) void bin_kernel(const int* __restrict__ src,
                                                   const int* __restrict__ dst,
                                                   const int* __restrict__ base,
                                                   int2* __restrict__ binned,
                                                   int e, int chunk, int NB,
                                                   int G) {
    __shared__ int cur[512];
    const int g = blockIdx.x;
    for (int b = threadIdx.x; b < NB; b += 1024) cur[b] = base[b * G + g];
    __syncthreads();
    const int lo = g * chunk;
    const int hi = min(lo + chunk, e);
    for (int i = lo + threadIdx.x; i < hi; i += 1024) {
        const int d = dst[i];
        const int p = atomicAdd(&cur[d >> 8], 1);
        binned[p] = make_int2(src[i], d);
    }
}

#define BUILD_CAP 6144
__global__ __launch_bounds__(256) void build_kernel(
    const int2* __restrict__ binned, const int* __restrict__ base,
    int* __restrict__ csr, int* __restrict__ deg, int* __restrict__ offs,
    int e, int n, int NB, int G) {
    __shared__ int2 ep[BUILD_CAP];
    __shared__ int degL[256];
    __shared__ int offL[256];
    __shared__ int curL[256];
    const int b = blockIdx.x;
    const int tid = threadIdx.x;
    const int start = base[b * G];
    const int end = (b == NB - 1) ? e : base[(b + 1) * G];
    const int cnt = end - start;
    const bool stage = (cnt <= BUILD_CAP);
    degL[tid] = 0;
    if (stage)
        for (int i = tid; i < cnt; i += 256) ep[i] = binned[start + i];
    __syncthreads();
    if (stage) {
        for (int i = tid; i < cnt; i += 256) atomicAdd(&degL[ep[i].y & 255], 1);
    } else {
        for (int i = tid; i < cnt; i += 256)
            atomicAdd(&degL[binned[start + i].y & 255], 1);
    }
    __syncthreads();
    const int v = degL[tid];
    offL[tid] = v;
    __syncthreads();
    for (int d = 1; d < 256; d <<= 1) {
        const int x = (tid >= d) ? offL[tid - d] : 0;
        __syncthreads();
        offL[tid] += x;
        __syncthreads();
    }
    const int excl = offL[tid] - v;
    curL[tid] = excl;
    const int node = (b << 8) + tid;
    if (node < n) {
        deg[node] = v;
        offs[node] = start + excl;
    }
    __syncthreads();
    if (stage) {
        for (int i = tid; i < cnt; i += 256) {
            const int p = atomicAdd(&curL[ep[i].y & 255], 1);
            csr[start + p] = ep[i].x;
        }
    } else {
        for (int i = tid; i < cnt; i += 256) {
            const int2 pr = binned[start + i];
            const int p = atomicAdd(&curL[pr.y & 255], 1);
            csr[start + p] = pr.x;
        }
    }
}

// --------- single-pass gather-aggregate + fused softmax denominator -------
// 4 nodes per wave, 16 lanes per node (lane = g*16 + s; node group g).
// Each lane covers R = HC/16 channels -> the whole wave's h-gather load
// instruction moves 4 x HC*2 bytes (1KB for layer 1): 4x fewer VMEM issue
// slots per edge than 1-node/wave, and softmax exp redundancy drops
// 16x -> 4x (4 lanes per (node,head) compute identical p, so the softmax
// denominator L is replicated -- still no cross-lane reduce needed).
// Degree imbalance is intra-wave: loop runs to max deg of the 4 nodes with
// index-clamped loads and p masked to 0 (~25% extra iterations for
// Poisson(16) degrees; each iteration is 4x denser, net win).
template <int H, int C, bool DO_ELU, bool OUT_BF16>
__global__ __launch_bounds__(64) void agg_kernel(
    const ushort_t* __restrict__ h, const float* __restrict__ a_src,
    const float* __restrict__ a_dst, const int* __restrict__ csr,
    const int* __restrict__ offs, const int* __restrict__ deg,
    const float* __restrict__ bias, void* __restrict__ outv, int n) {
    constexpr int HC = H * C;
    constexpr int R = HC / 16;   // 8 (layer1) or 4 (layer2) channels/lane
    constexpr int RW = R / 2;    // dwords per h access (4 or 2)
    constexpr int U = 4;         // edge batch
    const int lane = threadIdx.x;
    const int s = lane & 15;
    const int g = lane >> 4;
    const int dst = blockIdx.x * 4 + g;
    const int dstc = min(dst, n - 1);
    const int start = offs[dstc];
    const int dg = deg[dstc];
    const int ch0 = s * R;
    const int myh = (H > 1) ? (ch0 / C) : 0;
    const float advm = a_dst[dstc * H + myh];

    // wave-uniform loop bound: max degree over the 4 node groups
    int dmax = dg;
    dmax = max(dmax, __shfl_xor(dmax, 16));
    dmax = max(dmax, __shfl_xor(dmax, 32));
    dmax = __builtin_amdgcn_readfirstlane(dmax);

    float acc[R];
#pragma unroll
    for (int r = 0; r < R; ++r) acc[r] = 0.f;
    float L = 0.f;

    // ---- self-loop term ----
    {
        float e = a_src[dstc * H + myh] + advm;
        e = fmaxf(e, 0.2f * e);
        const float p = __expf(e);
        L += p;
        const ushort_t* hp = h + (size_t)((uint_t)dstc * HC) + ch0;
        if constexpr (RW == 4) {
            const uintx4 v = *(const uintx4*)hp;
#pragma unroll
            for (int w = 0; w < 4; ++w)
                unpack_fma(v[w], p, acc[2 * w], acc[2 * w + 1]);
        } else {
            const uintx2 v = *(const uintx2*)hp;
#pragma unroll
            for (int w = 0; w < 2; ++w)
                unpack_fma(v[w], p, acc[2 * w], acc[2 * w + 1]);
        }
    }

    const int dm1c = (dg > 0) ? dg - 1 : 0;

    for (int j0 = 0; j0 < dmax; j0 += U) {
        int sv[U];
#pragma unroll
        for (int u = 0; u < U; ++u)
            sv[u] = csr[start + min(j0 + u, dm1c)];
        float es[U];
#pragma unroll
        for (int u = 0; u < U; ++u) es[u] = a_src[sv[u] * H + myh];
        uint_t hv[U][RW];
#pragma unroll
        for (int u = 0; u < U; ++u) {
            const ushort_t* hp = h + (size_t)((uint_t)sv[u] * HC) + ch0;
            if constexpr (RW == 4) {
                const uintx4 v = *(const uintx4*)hp;
#pragma unroll
                for (int w = 0; w < 4; ++w) hv[u][w] = v[w];
            } else {
                const uintx2 v = *(const uintx2*)hp;
#pragma unroll
                for (int w = 0; w < 2; ++w) hv[u][w] = v[w];
            }
        }
        float p[U];
#pragma unroll
        for (int u = 0; u < U; ++u) {
            float e = es[u] + advm;
            e = fmaxf(e, 0.2f * e);
            const float pe = __expf(e);
            p[u] = (j0 + u < dg) ? pe : 0.f;
        }
#pragma unroll
        for (int u = 0; u < U; ++u) {
            L += p[u];
#pragma unroll
            for (int w = 0; w < RW; ++w)
                unpack_fma(hv[u][w], p[u], acc[2 * w], acc[2 * w + 1]);
        }
    }

    if (dst >= n) return;
    const float linv = 1.f / (L + 1e-16f);
    float r[R];
#pragma unroll
    for (int d = 0; d < R; ++d) {
        r[d] = acc[d] * linv + bias[ch0 + d];
        if (DO_ELU) r[d] = (r[d] > 0.f) ? r[d] : (__expf(r[d]) - 1.f);
    }
    if constexpr (OUT_BF16) {
        // R==8: pack into 4 dwords, one dwordx4 store per lane
        uintx4 o;
#pragma unroll
        for (int w = 0; w < 4; ++w)
            o[w] = (uint_t)f32_to_bf16(r[2 * w]) |
                   ((uint_t)f32_to_bf16(r[2 * w + 1]) << 16);
        *(uintx4*)((ushort_t*)outv + (size_t)dst * HC + ch0) = o;
    } else {
        // R==4: four f32, one dwordx4 store per lane
        fx4 o;
#pragma unroll
        for (int d = 0; d < 4; ++d) o[d] = r[d];
        *(fx4*)((float*)outv + (size_t)dst * HC + ch0) = o;
    }
}

// --------------------------------------------------------------------------
extern "C" void kernel_launch(void* const* d_in, const int* in_sizes, int n_in,
                              void* d_out, int out_size, void* d_ws,
                              size_t ws_size, hipStream_t stream) {
    const float* x = (const float*)d_in[0];
    const int* ei = (const int*)d_in[1];
    const float* W1 = (const float*)d_in[2];
    const float* att_s1 = (const float*)d_in[3];
    const float* att_d1 = (const float*)d_in[4];
    const float* b1 = (const float*)d_in[5];
    const float* W2 = (const float*)d_in[6];
    const float* att_s2 = (const float*)d_in[7];
    const float* att_d2 = (const float*)d_in[8];
    const float* b2 = (const float*)d_in[9];

    const int N = in_sizes[0] / 256;  // 100000
    const int E = in_sizes[1] / 2;    // 1600000
    const int* srcp = ei;
    const int* dstp = ei + E;

    const int NB = (N + 255) >> 8;  // 391 buckets of 256 nodes
    const int G = 128;
    const int NBG = NB * G;
    const int chunk = (E + G - 1) / G;
    const int nbs = (NBG + 1023) / 1024;

    // workspace layout
    float* as1 = (float*)d_ws;           // N*4
    float* ad1 = as1 + (size_t)N * 4;    // N*4
    float* as2 = ad1 + (size_t)N * 4;    // N
    float* ad2 = as2 + N;                // N
    int* histG = (int*)(ad2 + N);        // NBG
    int* base = histG + NBG;             // NBG
    int* sums = base + NBG;              // 128
    int* deg = sums + 128;               // N
    int* offs = deg + N;                 // N
    int* csr = offs + N;                 // E
    int2* binned = (int2*)(csr + E);     // E pairs (dead after build)
    ushort_t* h1 = (ushort_t*)binned;    // N*128 bf16 (overlays binned)
    ushort_t* h2 = h1 + (size_t)N * 128; // N*64 bf16
    ushort_t* h1p = h2 + (size_t)N * 64; // N*128 bf16 (agg1 out, gemm2 A)
    ushort_t* W1T = h1p + (size_t)N * 128;  // 128*256
    ushort_t* W2T = W1T + 128 * 256;        // 64*128

    // ---- weight transpose + bf16 convert ----
    convT_kernel<<<(256 * 128 + 255) / 256, 256, 0, stream>>>(W1, W1T, 256, 128);
    convT_kernel<<<(128 * 64 + 255) / 256, 256, 0, stream>>>(W2, W2T, 128, 64);

    // ---- CSR build (binned counting sort, no global atomics) ----
    hist_kernel<<<G, 1024, 0, stream>>>(dstp, histG, E, chunk, NB, G);
    scan1_kernel<<<nbs, 1024, 0, stream>>>(histG, base, sums, NBG);
    scan2_kernel<<<1, 128, 0, stream>>>(sums, nbs);
    scan3_kernel<<<nbs, 1024, 0, stream>>>(base, sums, NBG);
    bin_kernel<<<G, 1024, 0, stream>>>(srcp, dstp, base, binned, E, chunk, NB,
                                       G);
    build_kernel<<<NB, 256, 0, stream>>>(binned, base, csr, deg, offs, E, N,
                                         NB, G);

    const int gblk = (N + 127) / 128;  // 782 (128 rows per block)
    const int ablk = (N + 3) / 4;      // 25000 (4 nodes per wave)

    // ---- layer 1 ----
    gemm_lds_kernel<8, true, 256><<<gblk, 256, 0, stream>>>(x, W1T, h1, N);
    att_kernel<4, 32><<<(N * 4 + 255) / 256, 256, 0, stream>>>(h1, att_s1,
                                                               att_d1, as1,
                                                               ad1, N);
    agg_kernel<4, 32, true, true><<<ablk, 64, 0, stream>>>(h1, as1, ad1, csr,
                                                           offs, deg, b1, h1p,
                                                           N);

    // ---- layer 2 ----
    gemm_lds_kernel<4, false, 128><<<gblk, 256, 0, stream>>>(h1p, W2T, h2, N);
    att_kernel<1, 64><<<(N + 255) / 256, 256, 0, stream>>>(h2, att_s2, att_d2,
                                                           as2, ad2, N);
    agg_kernel<1, 64, false, false><<<ablk, 64, 0, stream>>>(h2, as2, ad2,
                                                             csr, offs, deg,
                                                             b2, d_out, N);
}